// Round 14
// baseline (388.864 us; speedup 1.0000x reference)
//
#include <hip/hip_runtime.h>
#include <math.h>

#define NN 16
#define FF 192001
#define NFFTN 384000
#define N1F 1024
#define N2F 375
#define NBLK 512
#define TWO_PI 6.283185307179586476925286766559

__constant__ float c_delays[16] = {809.f, 877.f, 937.f, 1049.f, 1151.f, 1249.f, 1373.f, 1499.f,
                                   1617.f, 1753.f, 1879.f, 2003.f, 2131.f, 2269.f, 2393.f, 2521.f};
__constant__ int c_idelays[16] = {809, 877, 937, 1049, 1151, 1249, 1373, 1499,
                                  1617, 1753, 1879, 2003, 2131, 2269, 2393, 2521};

typedef float v2f __attribute__((ext_vector_type(2)));

__device__ __forceinline__ float fastrcp(float x) {
#if __has_builtin(__builtin_amdgcn_rcpf)
  return __builtin_amdgcn_rcpf(x);
#else
  return 1.0f / x;
#endif
}

__device__ __forceinline__ float2 cmulf(float2 a, float2 b) {
  return make_float2(a.x * b.x - a.y * b.y, a.x * b.y + a.y * b.x);
}

// Device-scope grid barrier: fresh (cnt,flag) pair per use, pre-zeroed by the
// memset node. All NBLK blocks are co-resident (launch_bounds(256,2), 512
// blocks = 2/CU x 256 CU), so spinning is safe. Fences per Guideline 16.
__device__ __forceinline__ void gbar(unsigned* cnt, unsigned* flag) {
  __syncthreads();
  if (threadIdx.x == 0) {
    __threadfence();
    unsigned a = __hip_atomic_fetch_add(cnt, 1u, __ATOMIC_ACQ_REL, __HIP_MEMORY_SCOPE_AGENT);
    if (a == NBLK - 1) {
      __hip_atomic_store(flag, 1u, __ATOMIC_RELEASE, __HIP_MEMORY_SCOPE_AGENT);
    } else {
      while (__hip_atomic_load(flag, __ATOMIC_ACQUIRE, __HIP_MEMORY_SCOPE_AGENT) == 0u) {
        __builtin_amdgcn_s_sleep(1);
      }
    }
    __threadfence();
  }
  __syncthreads();
}

// ---- solve machinery (4 lanes/freq, 4 rows/lane, pivot-free GJ) ------------
template <int S>
__device__ __forceinline__ v2f bc4(v2f v) {
  v2f o;
  o[0] = __int_as_float(__builtin_amdgcn_ds_swizzle(__float_as_int(v[0]), (S << 5) | 0x1C));
  o[1] = __int_as_float(__builtin_amdgcn_ds_swizzle(__float_as_int(v[1]), (S << 5) | 0x1C));
  return o;
}

template <int K, int C>
struct ColLoop4 {
  static __device__ __forceinline__ void run(
      v2f (&M0)[17], v2f (&M1)[17], v2f (&M2)[17], v2f (&M3)[17],
      v2f f0a, v2f f0b, v2f f1a, v2f f1b, v2f f2a, v2f f2b, v2f f3a, v2f f3b) {
    constexpr int SL = K & 3, S = K >> 2;
    v2f pc;
    if constexpr (SL == 0) pc = bc4<S>(M0[C]);
    else if constexpr (SL == 1) pc = bc4<S>(M1[C]);
    else if constexpr (SL == 2) pc = bc4<S>(M2[C]);
    else pc = bc4<S>(M3[C]);
    v2f pcs = {pc[1], pc[0]};
    M0[C] = __builtin_elementwise_fma(f0a, pc, M0[C]);
    M0[C] = __builtin_elementwise_fma(f0b, pcs, M0[C]);
    M1[C] = __builtin_elementwise_fma(f1a, pc, M1[C]);
    M1[C] = __builtin_elementwise_fma(f1b, pcs, M1[C]);
    M2[C] = __builtin_elementwise_fma(f2a, pc, M2[C]);
    M2[C] = __builtin_elementwise_fma(f2b, pcs, M2[C]);
    M3[C] = __builtin_elementwise_fma(f3a, pc, M3[C]);
    M3[C] = __builtin_elementwise_fma(f3b, pcs, M3[C]);
    ColLoop4<K, C + 1>::run(M0, M1, M2, M3, f0a, f0b, f1a, f1b, f2a, f2b, f3a, f3b);
  }
};
template <int K>
struct ColLoop4<K, 17> {
  static __device__ __forceinline__ void run(v2f (&)[17], v2f (&)[17], v2f (&)[17], v2f (&)[17],
                                             v2f, v2f, v2f, v2f, v2f, v2f, v2f, v2f) {}
};

template <int K>
struct GJStep4 {
  static __device__ __forceinline__ void run(v2f (&M0)[17], v2f (&M1)[17], v2f (&M2)[17],
                                             v2f (&M3)[17], int s) {
    constexpr int SL = K & 3, S = K >> 2;
    v2f pk;
    if constexpr (SL == 0) pk = bc4<S>(M0[K]);
    else if constexpr (SL == 1) pk = bc4<S>(M1[K]);
    else if constexpr (SL == 2) pk = bc4<S>(M2[K]);
    else pk = bc4<S>(M3[K]);
    float invd = fastrcp(pk[0] * pk[0] + pk[1] * pk[1]);
    float rcx = pk[0] * invd, rcy = -pk[1] * invd;
    const bool inS = (s == S);
    v2f m0 = M0[K], m1 = M1[K], m2 = M2[K], m3 = M3[K];
    const bool p0 = inS && (SL == 0), p1 = inS && (SL == 1);
    const bool p2 = inS && (SL == 2), p3 = inS && (SL == 3);
    float f0x = p0 ? (1.0f - rcx) : (m0[0] * rcx - m0[1] * rcy);
    float f0y = p0 ? (-rcy)       : (m0[0] * rcy + m0[1] * rcx);
    float f1x = p1 ? (1.0f - rcx) : (m1[0] * rcx - m1[1] * rcy);
    float f1y = p1 ? (-rcy)       : (m1[0] * rcy + m1[1] * rcx);
    float f2x = p2 ? (1.0f - rcx) : (m2[0] * rcx - m2[1] * rcy);
    float f2y = p2 ? (-rcy)       : (m2[0] * rcy + m2[1] * rcx);
    float f3x = p3 ? (1.0f - rcx) : (m3[0] * rcx - m3[1] * rcy);
    float f3y = p3 ? (-rcy)       : (m3[0] * rcy + m3[1] * rcx);
    ColLoop4<K, K + 1>::run(M0, M1, M2, M3,
                            (v2f){-f0x, -f0x}, (v2f){f0y, -f0y},
                            (v2f){-f1x, -f1x}, (v2f){f1y, -f1y},
                            (v2f){-f2x, -f2x}, (v2f){f2y, -f2y},
                            (v2f){-f3x, -f3x}, (v2f){f3y, -f3y});
    GJStep4<K + 1>::run(M0, M1, M2, M3, s);
  }
};
template <>
struct GJStep4<16> {
  static __device__ __forceinline__ void run(v2f (&)[17], v2f (&)[17], v2f (&)[17], v2f (&)[17], int) {}
};

#define INITROW(Mj, jj, cj, sj)                                                   \
  do {                                                                            \
    const int rr_ = a0 + jj;                                                      \
    float4 q0 = AG4[rr_ * 4 + 0], q1 = AG4[rr_ * 4 + 1];                          \
    float4 q2 = AG4[rr_ * 4 + 2], q3 = AG4[rr_ * 4 + 3];                          \
    Mj[0]  = (v2f){(rr_ == 0  ? cj : 0.0f) - q0.x, (rr_ == 0  ? sj : 0.0f)};      \
    Mj[1]  = (v2f){(rr_ == 1  ? cj : 0.0f) - q0.y, (rr_ == 1  ? sj : 0.0f)};      \
    Mj[2]  = (v2f){(rr_ == 2  ? cj : 0.0f) - q0.z, (rr_ == 2  ? sj : 0.0f)};      \
    Mj[3]  = (v2f){(rr_ == 3  ? cj : 0.0f) - q0.w, (rr_ == 3  ? sj : 0.0f)};      \
    Mj[4]  = (v2f){(rr_ == 4  ? cj : 0.0f) - q1.x, (rr_ == 4  ? sj : 0.0f)};      \
    Mj[5]  = (v2f){(rr_ == 5  ? cj : 0.0f) - q1.y, (rr_ == 5  ? sj : 0.0f)};      \
    Mj[6]  = (v2f){(rr_ == 6  ? cj : 0.0f) - q1.z, (rr_ == 6  ? sj : 0.0f)};      \
    Mj[7]  = (v2f){(rr_ == 7  ? cj : 0.0f) - q1.w, (rr_ == 7  ? sj : 0.0f)};      \
    Mj[8]  = (v2f){(rr_ == 8  ? cj : 0.0f) - q2.x, (rr_ == 8  ? sj : 0.0f)};      \
    Mj[9]  = (v2f){(rr_ == 9  ? cj : 0.0f) - q2.y, (rr_ == 9  ? sj : 0.0f)};      \
    Mj[10] = (v2f){(rr_ == 10 ? cj : 0.0f) - q2.z, (rr_ == 10 ? sj : 0.0f)};      \
    Mj[11] = (v2f){(rr_ == 11 ? cj : 0.0f) - q2.w, (rr_ == 11 ? sj : 0.0f)};      \
    Mj[12] = (v2f){(rr_ == 12 ? cj : 0.0f) - q3.x, (rr_ == 12 ? sj : 0.0f)};      \
    Mj[13] = (v2f){(rr_ == 13 ? cj : 0.0f) - q3.y, (rr_ == 13 ? sj : 0.0f)};      \
    Mj[14] = (v2f){(rr_ == 14 ? cj : 0.0f) - q3.z, (rr_ == 14 ? sj : 0.0f)};      \
    Mj[15] = (v2f){(rr_ == 15 ? cj : 0.0f) - q3.w, (rr_ == 15 ? sj : 0.0f)};      \
    Mj[16] = (v2f){Bs[rr_], 0.0f};                                                \
  } while (0)

// ---------------------------------------------------------------------------
// The whole pipeline in ONE persistent kernel (512 co-resident blocks):
//  P0 per-block expm (redundant, concurrent)  P1 solve -> H + GT
//  [bar] P2 fftA (GT->AT)  [bar] P3 fftB (AT->h) + max  [bar] P4 normalize
// ---------------------------------------------------------------------------
template <bool CPLX>
__global__ __launch_bounds__(256, 2) void mega_kernel(
    const float* __restrict__ Bv, const float* __restrict__ Cv,
    const float* __restrict__ X, float* __restrict__ Hout,
    float* __restrict__ htail, float2* __restrict__ GT, float2* __restrict__ AT,
    unsigned* __restrict__ bar) {
  __shared__ __align__(16) char smem[21504];
  const int tid = threadIdx.x;
  unsigned* mx = bar + 6;

  // ---- P0: expm (every block computes its own copy; ~4 us, fully parallel)
  {
    double* S = (double*)smem;          // 16x16
    double* P = S + 256;
    double* E = P + 256;
    float* AGs = (float*)(smem + 8192); // persists through P1
    float* Bs = (float*)(smem + 9216);
    float* Cs = (float*)(smem + 9280);
    if (tid < 16) { Bs[tid] = Bv[tid]; Cs[tid] = Cv[tid]; }
    const int i = tid >> 4, j = tid & 15;
    double xu = (j > i) ? (double)X[i * 16 + j] : 0.0;
    double xl = (i > j) ? (double)X[j * 16 + i] : 0.0;
    double sv = (xu - xl) * (1.0 / 256.0);
    S[i * 16 + j] = sv;
    P[i * 16 + j] = sv;
    E[i * 16 + j] = (i == j ? 1.0 : 0.0) + sv;
    __syncthreads();
    for (int k = 2; k <= 24; ++k) {
      double acc = 0.0;
#pragma unroll
      for (int l = 0; l < 16; ++l) acc += P[i * 16 + l] * S[l * 16 + j];
      acc /= (double)k;
      __syncthreads();
      P[i * 16 + j] = acc;
      E[i * 16 + j] += acc;
      __syncthreads();
    }
    for (int t = 0; t < 8; ++t) {
      double acc = 0.0;
#pragma unroll
      for (int l = 0; l < 16; ++l) acc += E[i * 16 + l] * E[l * 16 + j];
      __syncthreads();
      E[i * 16 + j] = acc;
      __syncthreads();
    }
    double g = exp((double)c_delays[j] * log(0.9998));
    AGs[i * 16 + j] = (float)(E[i * 16 + j] * g);
    __syncthreads();
  }

  // ---- P1: solve, grid-stride over 3001 virtual blocks of 64 freqs
  {
    const float* AGs = (const float*)(smem + 8192);
    const float* Bs = (const float*)(smem + 9216);
    const float* Cs = (const float*)(smem + 9280);
    const float4* AG4 = (const float4*)AGs;
    const int s = tid & 3;
    const int a0 = s << 2;
    const float k2r = (float)(TWO_PI / (double)NFFTN);
    for (int vb = blockIdx.x; vb < (FF + 63) / 64; vb += NBLK) {
      int f = vb * 64 + (tid >> 2);
      const bool active = (f < FF);
      if (!active) f = FF - 1;
      int ph0 = (c_idelays[a0 + 0] * f) % NFFTN;
      int ph1 = (c_idelays[a0 + 1] * f) % NFFTN;
      int ph2 = (c_idelays[a0 + 2] * f) % NFFTN;
      int ph3 = (c_idelays[a0 + 3] * f) % NFFTN;
      float c0, s0, c1, s1, c2, s2, c3, s3;
      sincosf((float)ph0 * k2r, &s0, &c0);
      sincosf((float)ph1 * k2r, &s1, &c1);
      sincosf((float)ph2 * k2r, &s2, &c2);
      sincosf((float)ph3 * k2r, &s3, &c3);
      v2f M0[17], M1[17], M2[17], M3[17];
      INITROW(M0, 0, c0, s0);
      INITROW(M1, 1, c1, s1);
      INITROW(M2, 2, c2, s2);
      INITROW(M3, 3, c3, s3);
      GJStep4<0>::run(M0, M1, M2, M3, s);
      const float cc0 = Cs[a0 + 0], cc1 = Cs[a0 + 1], cc2 = Cs[a0 + 2], cc3 = Cs[a0 + 3];
      v2f h0 = {M0[16][0] * cc0, M0[16][1] * cc0};
      v2f h1 = {M1[16][0] * cc1, M1[16][1] * cc1};
      v2f h2 = {M2[16][0] * cc2, M2[16][1] * cc2};
      v2f h3 = {M3[16][0] * cc3, M3[16][1] * cc3};
      if (active) {
        if (CPLX) {
          float4* dst = (float4*)((float2*)Hout + (size_t)f * 16 + a0);
          dst[0] = (float4){h0[0], h0[1], h1[0], h1[1]};
          dst[1] = (float4){h2[0], h2[1], h3[0], h3[1]};
        } else {
          *(float4*)&Hout[(size_t)f * 16 + a0] = (float4){h0[0], h1[0], h2[0], h3[0]};
        }
      }
      float sx = h0[0] + h1[0] + h2[0] + h3[0];
      float sy = h0[1] + h1[1] + h2[1] + h3[1];
      sx += __shfl_xor(sx, 1, 4); sy += __shfl_xor(sy, 1, 4);
      sx += __shfl_xor(sx, 2, 4); sy += __shfl_xor(sy, 2, 4);
      if (active && s == 0) {
        if (f == 0 || f == 192000) sy = 0.0f;
        GT[(f % N2F) * 1024 + f / N2F] = make_float2(sx, sy);
        if (f > 0 && f < 192000) {
          int m2 = NFFTN - f;
          GT[(m2 % N2F) * 1024 + m2 / N2F] = make_float2(sx, -sy);
        }
      }
    }
  }
  gbar(bar + 0, bar + 1);

  // ---- P2: fftA — 1024-pt inverse FFT per k2 (375 working blocks)
  if (blockIdx.x < N2F) {
    float2* buf0 = (float2*)smem;            // [1024]
    float2* buf1 = buf0 + 1024;              // [1024]  (16384 B total)
    float2* wtab = (float2*)(smem + 16384);  // [512]
    float2* wA = (float2*)(smem + 20480);    // [32]
    float2* wB = (float2*)(smem + 20736);    // [32]
    const int k2 = blockIdx.x;
#pragma unroll
    for (int rr = 0; rr < 4; ++rr) {
      int k1 = tid + 256 * rr;
      buf0[k1] = GT[k2 * 1024 + k1];
    }
    {
      float s_, c_;
      sincosf((float)tid * (float)(TWO_PI / 1024.0), &s_, &c_);
      wtab[tid] = make_float2(c_, s_);
      sincosf((float)(tid + 256) * (float)(TWO_PI / 1024.0), &s_, &c_);
      wtab[tid + 256] = make_float2(c_, s_);
    }
    if (tid < 64) {
      double base = TWO_PI * (double)k2 / (double)NFFTN;
      float s_, c_;
      if (tid < 32) {
        sincosf((float)(base * (double)tid), &s_, &c_);
        wA[tid] = make_float2(c_, s_);
      } else {
        int j = tid - 32;
        sincosf((float)(base * 32.0 * (double)j), &s_, &c_);
        wB[j] = make_float2(c_, s_);
      }
    }
    __syncthreads();
    float2* bsrc = buf0;
    float2* bdst = buf1;
#pragma unroll
    for (int st = 0; st < 10; ++st) {
      const int sS = 1 << st;
      const int m = 512 >> st;
#pragma unroll
      for (int rr2 = 0; rr2 < 2; ++rr2) {
        int jj = tid + 256 * rr2;
        int p = jj >> st;
        int q = jj & (sS - 1);
        float2 w = wtab[p << st];
        float2 a = bsrc[q + sS * p];
        float2 b = bsrc[q + sS * (p + m)];
        float2 sum = make_float2(a.x + b.x, a.y + b.y);
        float2 d = make_float2(a.x - b.x, a.y - b.y);
        float2 wd = make_float2(d.x * w.x - d.y * w.y, d.x * w.y + d.y * w.x);
        bdst[q + sS * (2 * p)] = sum;
        bdst[q + sS * (2 * p + 1)] = wd;
      }
      __syncthreads();
      float2* tmp = bsrc; bsrc = bdst; bdst = tmp;
    }
#pragma unroll
    for (int rr = 0; rr < 4; ++rr) {
      int t1 = tid + 256 * rr;
      float2 vz = bsrc[t1];
      float2 tw = cmulf(wA[t1 & 31], wB[t1 >> 5]);
      AT[k2 * 1024 + t1] = cmulf(vz, tw);
    }
  }
  gbar(bar + 2, bar + 3);

  // ---- P3: fftB — 375-pt inverse DFT (25x15) per t1, 2 t1 per block + max
  {
    float2* tw = (float2*)smem;              // [375] persists across t1 iters
    float2* bv = (float2*)(smem + 3072);     // [375]
    float2* Y  = (float2*)(smem + 6144);     // [375]
    float*  wmax = (float*)(smem + 9216);    // [4]
    for (int j = tid; j < N2F; j += 256) {
      float ang = (float)(TWO_PI * (double)j / 375.0);
      float s_, c_;
      sincosf(ang, &s_, &c_);
      tw[j] = make_float2(c_, s_);
    }
    float m = 0.0f;
    for (int t1 = blockIdx.x; t1 < N1F; t1 += NBLK) {
      __syncthreads();
      for (int j = tid; j < N2F; j += 256) bv[j] = AT[j * 1024 + t1];
      __syncthreads();
      for (int j = tid; j < N2F; j += 256) {
        const int a = j / 15, u = j - 15 * a;
        float ax = 0.f, ay = 0.f;
        int i15 = 0;
#pragma unroll
        for (int b = 0; b < 15; ++b) {
          float2 x = bv[a + 25 * b];
          float2 w = tw[i15 * 25];
          ax += x.x * w.x - x.y * w.y;
          ay += x.x * w.y + x.y * w.x;
          i15 += u;
          if (i15 >= 15) i15 -= 15;
        }
        Y[j] = make_float2(ax, ay);
      }
      __syncthreads();
      for (int t = tid; t < N2F; t += 256) {
        const int u = t % 15;
        float acc = 0.f;
        int idx = 0;
#pragma unroll
        for (int a = 0; a < 25; ++a) {
          float2 y = Y[a * 15 + u];
          float2 w = tw[idx];
          acc += y.x * w.x - y.y * w.y;
          idx += t;
          if (idx >= 375) idx -= 375;
        }
        float hv = acc * (1.0f / (float)NFFTN);
        htail[t1 + 1024 * t] = hv;
        m = fmaxf(m, fabsf(hv));
      }
    }
    __syncthreads();
#pragma unroll
    for (int off = 32; off > 0; off >>= 1) m = fmaxf(m, __shfl_xor(m, off, 64));
    if ((tid & 63) == 0) wmax[tid >> 6] = m;
    __syncthreads();
    if (tid == 0) {
      float mm = fmaxf(fmaxf(wmax[0], wmax[1]), fmaxf(wmax[2], wmax[3]));
      atomicMax(mx, __float_as_uint(mm));
    }
  }
  gbar(bar + 4, bar + 5);

  // ---- P4: normalize h
  {
    float mv = __uint_as_float(
        __hip_atomic_load(mx, __ATOMIC_ACQUIRE, __HIP_MEMORY_SCOPE_AGENT));
    for (int i = blockIdx.x * 256 + tid; i < NFFTN; i += NBLK * 256)
      htail[i] = htail[i] / mv;
  }
}

extern "C" void kernel_launch(void* const* d_in, const int* in_sizes, int n_in,
                              void* d_out, int out_size, void* d_ws, size_t ws_size,
                              hipStream_t stream) {
  (void)in_sizes; (void)n_in; (void)ws_size;
  const float* Bv = (const float*)d_in[2];
  const float* Cv = (const float*)d_in[3];
  const float* X  = (const float*)d_in[4];
  float* out = (float*)d_out;
  char* ws = (char*)d_ws;
  unsigned* bar = (unsigned*)ws;            // cnt/flag x3 + mx (zeroed below)
  float2* GT = (float2*)(ws + 1024);        // 375*1024 float2 = 3,072,000 B
  float2* AT = (float2*)(ws + 1024 + 3072000);
  float* htail = out + (out_size - NFFTN);

  hipMemsetAsync(bar, 0, 64, stream);
  if (out_size >= 2 * FF * NN + NFFTN) {
    mega_kernel<true><<<NBLK, 256, 0, stream>>>(Bv, Cv, X, out, htail, GT, AT, bar);
  } else {
    mega_kernel<false><<<NBLK, 256, 0, stream>>>(Bv, Cv, X, out, htail, GT, AT, bar);
  }
}

// Round 15
// 155.046 us; speedup vs baseline: 2.5081x; 2.5081x over previous
//
#include <hip/hip_runtime.h>
#include <math.h>

#define NN 16
#define FF 192001
#define NFFTN 384000
#define N1F 1024
#define N2F 375
#define TWO_PI 6.283185307179586476925286766559

__constant__ float c_delays[16] = {809.f, 877.f, 937.f, 1049.f, 1151.f, 1249.f, 1373.f, 1499.f,
                                   1617.f, 1753.f, 1879.f, 2003.f, 2131.f, 2269.f, 2393.f, 2521.f};
__constant__ int c_idelays[16] = {809, 877, 937, 1049, 1151, 1249, 1373, 1499,
                                  1617, 1753, 1879, 2003, 2131, 2269, 2393, 2521};

typedef float v2f __attribute__((ext_vector_type(2)));

__device__ __forceinline__ float fastrcp(float x) {
#if __has_builtin(__builtin_amdgcn_rcpf)
  return __builtin_amdgcn_rcpf(x);
#else
  return 1.0f / x;
#endif
}

__device__ __forceinline__ float2 cmulf(float2 a, float2 b) {
  return make_float2(a.x * b.x - a.y * b.y, a.x * b.y + a.y * b.x);
}

// ---------------------------------------------------------------------------
// A = expm(skew(X)) in double (scaling-squaring Taylor); AG = A*diag(gamma).
// Also zeroes the global-max slot (ws is re-poisoned before every call).
// ---------------------------------------------------------------------------
__global__ void expm_kernel(const float* __restrict__ X, float* __restrict__ AGout,
                            unsigned* __restrict__ mx) {
  if (threadIdx.x == 0) *mx = 0u;
  __shared__ double S[16][16], P[16][16], E[16][16];
  const int i = threadIdx.x >> 4, j = threadIdx.x & 15;
  double xu = (j > i) ? (double)X[i * 16 + j] : 0.0;
  double xl = (i > j) ? (double)X[j * 16 + i] : 0.0;
  double s = (xu - xl) * (1.0 / 256.0);
  S[i][j] = s;
  P[i][j] = s;
  E[i][j] = (i == j ? 1.0 : 0.0) + s;
  __syncthreads();
  for (int k = 2; k <= 24; ++k) {
    double acc = 0.0;
#pragma unroll
    for (int l = 0; l < 16; ++l) acc += P[i][l] * S[l][j];
    acc /= (double)k;
    __syncthreads();
    P[i][j] = acc;
    E[i][j] += acc;
    __syncthreads();
  }
  for (int t = 0; t < 8; ++t) {
    double acc = 0.0;
#pragma unroll
    for (int l = 0; l < 16; ++l) acc += E[i][l] * E[l][j];
    __syncthreads();
    E[i][j] = acc;
    __syncthreads();
  }
  double g = exp((double)c_delays[j] * log(0.9998));
  AGout[i * 16 + j] = (float)(E[i][j] * g);
}

// ---------------------------------------------------------------------------
// Broadcast lane S within 4-lane groups: j = (i & 0x1C) | S.
// ---------------------------------------------------------------------------
template <int S>
__device__ __forceinline__ v2f bc4(v2f v) {
  v2f o;
  o[0] = __int_as_float(__builtin_amdgcn_ds_swizzle(__float_as_int(v[0]), (S << 5) | 0x1C));
  o[1] = __int_as_float(__builtin_amdgcn_ds_swizzle(__float_as_int(v[1]), (S << 5) | 0x1C));
  return o;
}

// Column loop of GJ step K: one broadcast feeds FOUR owned rows.
template <int K, int C>
struct ColLoop4 {
  static __device__ __forceinline__ void run(
      v2f (&M0)[17], v2f (&M1)[17], v2f (&M2)[17], v2f (&M3)[17],
      v2f f0a, v2f f0b, v2f f1a, v2f f1b, v2f f2a, v2f f2b, v2f f3a, v2f f3b) {
    constexpr int SL = K & 3, S = K >> 2;
    v2f pc;
    if constexpr (SL == 0) pc = bc4<S>(M0[C]);
    else if constexpr (SL == 1) pc = bc4<S>(M1[C]);
    else if constexpr (SL == 2) pc = bc4<S>(M2[C]);
    else pc = bc4<S>(M3[C]);
    v2f pcs = {pc[1], pc[0]};
    M0[C] = __builtin_elementwise_fma(f0a, pc, M0[C]);
    M0[C] = __builtin_elementwise_fma(f0b, pcs, M0[C]);
    M1[C] = __builtin_elementwise_fma(f1a, pc, M1[C]);
    M1[C] = __builtin_elementwise_fma(f1b, pcs, M1[C]);
    M2[C] = __builtin_elementwise_fma(f2a, pc, M2[C]);
    M2[C] = __builtin_elementwise_fma(f2b, pcs, M2[C]);
    M3[C] = __builtin_elementwise_fma(f3a, pc, M3[C]);
    M3[C] = __builtin_elementwise_fma(f3b, pcs, M3[C]);
    ColLoop4<K, C + 1>::run(M0, M1, M2, M3, f0a, f0b, f1a, f1b, f2a, f2b, f3a, f3b);
  }
};
template <int K>
struct ColLoop4<K, 17> {
  static __device__ __forceinline__ void run(v2f (&)[17], v2f (&)[17], v2f (&)[17], v2f (&)[17],
                                             v2f, v2f, v2f, v2f, v2f, v2f, v2f, v2f) {}
};

// Pivot-free GJ step K. Pivot row K lives in lane K>>2, slot K&3.
template <int K>
struct GJStep4 {
  static __device__ __forceinline__ void run(v2f (&M0)[17], v2f (&M1)[17], v2f (&M2)[17],
                                             v2f (&M3)[17], int s) {
    constexpr int SL = K & 3, S = K >> 2;
    v2f pk;
    if constexpr (SL == 0) pk = bc4<S>(M0[K]);
    else if constexpr (SL == 1) pk = bc4<S>(M1[K]);
    else if constexpr (SL == 2) pk = bc4<S>(M2[K]);
    else pk = bc4<S>(M3[K]);
    float invd = fastrcp(pk[0] * pk[0] + pk[1] * pk[1]);
    float rcx = pk[0] * invd, rcy = -pk[1] * invd;
    const bool inS = (s == S);
    v2f m0 = M0[K], m1 = M1[K], m2 = M2[K], m3 = M3[K];
    const bool p0 = inS && (SL == 0), p1 = inS && (SL == 1);
    const bool p2 = inS && (SL == 2), p3 = inS && (SL == 3);
    float f0x = p0 ? (1.0f - rcx) : (m0[0] * rcx - m0[1] * rcy);
    float f0y = p0 ? (-rcy)       : (m0[0] * rcy + m0[1] * rcx);
    float f1x = p1 ? (1.0f - rcx) : (m1[0] * rcx - m1[1] * rcy);
    float f1y = p1 ? (-rcy)       : (m1[0] * rcy + m1[1] * rcx);
    float f2x = p2 ? (1.0f - rcx) : (m2[0] * rcx - m2[1] * rcy);
    float f2y = p2 ? (-rcy)       : (m2[0] * rcy + m2[1] * rcx);
    float f3x = p3 ? (1.0f - rcx) : (m3[0] * rcx - m3[1] * rcy);
    float f3y = p3 ? (-rcy)       : (m3[0] * rcy + m3[1] * rcx);
    ColLoop4<K, K + 1>::run(M0, M1, M2, M3,
                            (v2f){-f0x, -f0x}, (v2f){f0y, -f0y},
                            (v2f){-f1x, -f1x}, (v2f){f1y, -f1y},
                            (v2f){-f2x, -f2x}, (v2f){f2y, -f2y},
                            (v2f){-f3x, -f3x}, (v2f){f3y, -f3y});
    GJStep4<K + 1>::run(M0, M1, M2, M3, s);
  }
};
template <>
struct GJStep4<16> {
  static __device__ __forceinline__ void run(v2f (&)[17], v2f (&)[17], v2f (&)[17], v2f (&)[17], int) {}
};

#define INITROW(Mj, jj, cj, sj)                                                   \
  do {                                                                            \
    const int rr_ = a0 + jj;                                                      \
    float4 q0 = AG4[rr_ * 4 + 0], q1 = AG4[rr_ * 4 + 1];                          \
    float4 q2 = AG4[rr_ * 4 + 2], q3 = AG4[rr_ * 4 + 3];                          \
    Mj[0]  = (v2f){(rr_ == 0  ? cj : 0.0f) - q0.x, (rr_ == 0  ? sj : 0.0f)};      \
    Mj[1]  = (v2f){(rr_ == 1  ? cj : 0.0f) - q0.y, (rr_ == 1  ? sj : 0.0f)};      \
    Mj[2]  = (v2f){(rr_ == 2  ? cj : 0.0f) - q0.z, (rr_ == 2  ? sj : 0.0f)};      \
    Mj[3]  = (v2f){(rr_ == 3  ? cj : 0.0f) - q0.w, (rr_ == 3  ? sj : 0.0f)};      \
    Mj[4]  = (v2f){(rr_ == 4  ? cj : 0.0f) - q1.x, (rr_ == 4  ? sj : 0.0f)};      \
    Mj[5]  = (v2f){(rr_ == 5  ? cj : 0.0f) - q1.y, (rr_ == 5  ? sj : 0.0f)};      \
    Mj[6]  = (v2f){(rr_ == 6  ? cj : 0.0f) - q1.z, (rr_ == 6  ? sj : 0.0f)};      \
    Mj[7]  = (v2f){(rr_ == 7  ? cj : 0.0f) - q1.w, (rr_ == 7  ? sj : 0.0f)};      \
    Mj[8]  = (v2f){(rr_ == 8  ? cj : 0.0f) - q2.x, (rr_ == 8  ? sj : 0.0f)};      \
    Mj[9]  = (v2f){(rr_ == 9  ? cj : 0.0f) - q2.y, (rr_ == 9  ? sj : 0.0f)};      \
    Mj[10] = (v2f){(rr_ == 10 ? cj : 0.0f) - q2.z, (rr_ == 10 ? sj : 0.0f)};      \
    Mj[11] = (v2f){(rr_ == 11 ? cj : 0.0f) - q2.w, (rr_ == 11 ? sj : 0.0f)};      \
    Mj[12] = (v2f){(rr_ == 12 ? cj : 0.0f) - q3.x, (rr_ == 12 ? sj : 0.0f)};      \
    Mj[13] = (v2f){(rr_ == 13 ? cj : 0.0f) - q3.y, (rr_ == 13 ? sj : 0.0f)};      \
    Mj[14] = (v2f){(rr_ == 14 ? cj : 0.0f) - q3.z, (rr_ == 14 ? sj : 0.0f)};      \
    Mj[15] = (v2f){(rr_ == 15 ? cj : 0.0f) - q3.w, (rr_ == 15 ? sj : 0.0f)};      \
    Mj[16] = (v2f){Bs[rr_], 0.0f};                                                \
  } while (0)

template <bool CPLX>
__global__ __launch_bounds__(256, 2) void solve_kernel(
    const float* __restrict__ Bv, const float* __restrict__ Cv,
    const float* __restrict__ AGin, float* __restrict__ Hout,
    float2* __restrict__ G) {
  __shared__ float AGs[16][16];
  __shared__ float Bs[16], Cs[16];
  const int tid = threadIdx.x;
  AGs[tid >> 4][tid & 15] = AGin[tid];
  if (tid < 16) { Bs[tid] = Bv[tid]; Cs[tid] = Cv[tid]; }
  const int s = tid & 3;
  const int a0 = s << 2;  // my 4 rows: a0..a0+3
  int f = blockIdx.x * 64 + (tid >> 2);
  const bool active = (f < FF);
  if (!active) f = FF - 1;
  __syncthreads();

  int ph0 = (c_idelays[a0 + 0] * f) % NFFTN;
  int ph1 = (c_idelays[a0 + 1] * f) % NFFTN;
  int ph2 = (c_idelays[a0 + 2] * f) % NFFTN;
  int ph3 = (c_idelays[a0 + 3] * f) % NFFTN;
  const float k2r = (float)(TWO_PI / (double)NFFTN);
  float c0, s0, c1, s1, c2, s2, c3, s3;
  sincosf((float)ph0 * k2r, &s0, &c0);
  sincosf((float)ph1 * k2r, &s1, &c1);
  sincosf((float)ph2 * k2r, &s2, &c2);
  sincosf((float)ph3 * k2r, &s3, &c3);

  const float4* AG4 = (const float4*)&AGs[0][0];
  v2f M0[17], M1[17], M2[17], M3[17];
  INITROW(M0, 0, c0, s0);
  INITROW(M1, 1, c1, s1);
  INITROW(M2, 2, c2, s2);
  INITROW(M3, 3, c3, s3);

  GJStep4<0>::run(M0, M1, M2, M3, s);

  const float cc0 = Cs[a0 + 0], cc1 = Cs[a0 + 1], cc2 = Cs[a0 + 2], cc3 = Cs[a0 + 3];
  v2f h0 = {M0[16][0] * cc0, M0[16][1] * cc0};
  v2f h1 = {M1[16][0] * cc1, M1[16][1] * cc1};
  v2f h2 = {M2[16][0] * cc2, M2[16][1] * cc2};
  v2f h3 = {M3[16][0] * cc3, M3[16][1] * cc3};
  if (active) {
    if (CPLX) {
      float4* dst = (float4*)((float2*)Hout + (size_t)f * 16 + a0);
      dst[0] = (float4){h0[0], h0[1], h1[0], h1[1]};
      dst[1] = (float4){h2[0], h2[1], h3[0], h3[1]};
    } else {
      *(float4*)&Hout[(size_t)f * 16 + a0] = (float4){h0[0], h1[0], h2[0], h3[0]};
    }
  }
  float sx = h0[0] + h1[0] + h2[0] + h3[0];
  float sy = h0[1] + h1[1] + h2[1] + h3[1];
  sx += __shfl_xor(sx, 1, 4); sy += __shfl_xor(sy, 1, 4);
  sx += __shfl_xor(sx, 2, 4); sy += __shfl_xor(sy, 2, 4);
  if (active && s == 0) {
    if (f == 0 || f == 192000) sy = 0.0f;  // c2r ignores DC/Nyquist imag
    G[f] = make_float2(sx, sy);
    if (f > 0 && f < 192000) G[NFFTN - f] = make_float2(sx, -sy);
  }
}

// ---------------------------------------------------------------------------
// T1: GT[k2*1024 + k1] = G[k2 + 375*k1]; LDS 32x32 tiles, both sides coalesced.
// ---------------------------------------------------------------------------
__global__ __launch_bounds__(256) void t1_kernel(const float2* __restrict__ G,
                                                 float2* __restrict__ GT) {
  __shared__ float2 tile[32][33];
  const int k1b = blockIdx.x * 32, k2b = blockIdx.y * 32;
  const int tx = threadIdx.x & 31, ty = threadIdx.x >> 5;
#pragma unroll
  for (int i = 0; i < 4; ++i) {
    int k1 = k1b + ty + 8 * i;
    int k2 = k2b + tx;
    if (k2 < N2F) tile[ty + 8 * i][tx] = G[k2 + N2F * k1];
  }
  __syncthreads();
#pragma unroll
  for (int i = 0; i < 4; ++i) {
    int k2 = k2b + ty + 8 * i;
    int k1 = k1b + tx;
    if (k2 < N2F) GT[k2 * 1024 + k1] = tile[tx][ty + 8 * i];
  }
}

// ---------------------------------------------------------------------------
// Stage A: per k2, 1024-point inverse FFT (Stockham, LDS) + outer twiddle.
// Coalesced read GT[k2*1024+k1]; coalesced write AT[k2*1024+t1].
// ---------------------------------------------------------------------------
__global__ __launch_bounds__(256) void fftA_kernel(const float2* __restrict__ GT,
                                                   float2* __restrict__ AT) {
  __shared__ float2 buf[2][1024];
  __shared__ float2 wtab[512];
  __shared__ float2 wA[32], wB[32];
  const int k2 = blockIdx.x;
  const int tid = threadIdx.x;
#pragma unroll
  for (int rr = 0; rr < 4; ++rr) {
    int k1 = tid + 256 * rr;
    buf[0][k1] = GT[k2 * 1024 + k1];
  }
  {
    float s_, c_;
    sincosf((float)tid * (float)(TWO_PI / 1024.0), &s_, &c_);
    wtab[tid] = make_float2(c_, s_);
    sincosf((float)(tid + 256) * (float)(TWO_PI / 1024.0), &s_, &c_);
    wtab[tid + 256] = make_float2(c_, s_);
  }
  if (tid < 64) {
    double base = TWO_PI * (double)k2 / (double)NFFTN;
    float s_, c_;
    if (tid < 32) {
      sincosf((float)(base * (double)tid), &s_, &c_);
      wA[tid] = make_float2(c_, s_);
    } else {
      int j = tid - 32;
      sincosf((float)(base * 32.0 * (double)j), &s_, &c_);
      wB[j] = make_float2(c_, s_);
    }
  }
  __syncthreads();
  int src = 0;
#pragma unroll
  for (int st = 0; st < 10; ++st) {
    const int sS = 1 << st;
    const int m = 512 >> st;
#pragma unroll
    for (int rr2 = 0; rr2 < 2; ++rr2) {
      int jj = tid + 256 * rr2;
      int p = jj >> st;
      int q = jj & (sS - 1);
      float2 w = wtab[p << st];
      float2 a = buf[src][q + sS * p];
      float2 b = buf[src][q + sS * (p + m)];
      float2 sum = make_float2(a.x + b.x, a.y + b.y);
      float2 d = make_float2(a.x - b.x, a.y - b.y);
      float2 wd = make_float2(d.x * w.x - d.y * w.y, d.x * w.y + d.y * w.x);
      buf[src ^ 1][q + sS * (2 * p)] = sum;
      buf[src ^ 1][q + sS * (2 * p + 1)] = wd;
    }
    __syncthreads();
    src ^= 1;
  }
#pragma unroll
  for (int rr = 0; rr < 4; ++rr) {
    int t1 = tid + 256 * rr;
    float2 vz = buf[src][t1];
    float2 tw = cmulf(wA[t1 & 31], wB[t1 >> 5]);
    AT[k2 * 1024 + t1] = cmulf(vz, tw);
  }
}

// ---------------------------------------------------------------------------
// T2: Bb[t1*375 + k2] = AT[k2*1024 + t1]; LDS 32x32 tiles, both sides coalesced.
// ---------------------------------------------------------------------------
__global__ __launch_bounds__(256) void t2_kernel(const float2* __restrict__ AT,
                                                 float2* __restrict__ Bb) {
  __shared__ float2 tile[32][33];
  const int t1b = blockIdx.x * 32, k2b = blockIdx.y * 32;
  const int tx = threadIdx.x & 31, ty = threadIdx.x >> 5;
#pragma unroll
  for (int i = 0; i < 4; ++i) {
    int k2 = k2b + ty + 8 * i;
    int t1 = t1b + tx;
    if (k2 < N2F) tile[ty + 8 * i][tx] = AT[k2 * 1024 + t1];
  }
  __syncthreads();
#pragma unroll
  for (int i = 0; i < 4; ++i) {
    int t1 = t1b + ty + 8 * i;
    int k2 = k2b + tx;
    if (k2 < N2F) Bb[t1 * N2F + k2] = tile[tx][ty + 8 * i];
  }
}

// ---------------------------------------------------------------------------
// Stage B: per t1, 375-point inverse DFT (25x15 mixed radix). COALESCED write
// to htmp[t1*375 + t2] (round-14 lesson: the old stride-4KB h write was a
// 24.6 MB scattered stream = the whole "irreducible" tail). Block max -> mx.
// ---------------------------------------------------------------------------
__global__ __launch_bounds__(384) void fftB_kernel(const float2* __restrict__ Bb,
                                                   float* __restrict__ htmp,
                                                   unsigned* __restrict__ mx) {
  __shared__ float2 bv[375];
  __shared__ float2 tw[375];
  __shared__ float2 Y[375];
  __shared__ float wmax[6];
  const int t1 = blockIdx.x;
  const int tid = threadIdx.x;
  if (tid < 375) {
    bv[tid] = Bb[t1 * N2F + tid];
    float ang = (float)(TWO_PI * (double)tid / 375.0);
    float s, c;
    sincosf(ang, &s, &c);
    tw[tid] = make_float2(c, s);
  }
  __syncthreads();
  if (tid < 375) {
    const int a = tid / 15, u = tid - 15 * a;
    float ax = 0.f, ay = 0.f;
    int i15 = 0;
#pragma unroll
    for (int b = 0; b < 15; ++b) {
      float2 x = bv[a + 25 * b];
      float2 w = tw[i15 * 25];
      ax += x.x * w.x - x.y * w.y;
      ay += x.x * w.y + x.y * w.x;
      i15 += u;
      if (i15 >= 15) i15 -= 15;
    }
    Y[tid] = make_float2(ax, ay);
  }
  __syncthreads();
  float m = 0.0f;
  if (tid < 375) {
    const int t = tid;
    const int u = t % 15;
    float acc = 0.f;
    int idx = 0;
#pragma unroll
    for (int a = 0; a < 25; ++a) {
      float2 y = Y[a * 15 + u];
      float2 w = tw[idx];
      acc += y.x * w.x - y.y * w.y;
      idx += t;
      if (idx >= 375) idx -= 375;
    }
    float hv = acc * (1.0f / (float)NFFTN);
    htmp[t1 * N2F + t] = hv;   // contiguous in t -> coalesced
    m = fabsf(hv);
  }
#pragma unroll
  for (int off = 32; off > 0; off >>= 1) m = fmaxf(m, __shfl_xor(m, off, 64));
  if ((tid & 63) == 0) wmax[tid >> 6] = m;
  __syncthreads();
  if (tid == 0) {
    float mm = wmax[0];
#pragma unroll
    for (int w = 1; w < 6; ++w) mm = fmaxf(mm, wmax[w]);
    atomicMax(mx, __float_as_uint(mm));
  }
}

// ---------------------------------------------------------------------------
// T3: h[t1 + 1024*t2] = htmp[t1*375 + t2] / max. LDS-tiled transpose, both
// sides coalesced, normalize fused (mx complete: fftB is a prior node).
// ---------------------------------------------------------------------------
__global__ __launch_bounds__(256) void t3_kernel(const float* __restrict__ htmp,
                                                 const unsigned* __restrict__ mx,
                                                 float* __restrict__ h) {
  __shared__ float tile[32][33];
  const int t1b = blockIdx.x * 32, t2b = blockIdx.y * 32;
  const int tx = threadIdx.x & 31, ty = threadIdx.x >> 5;
#pragma unroll
  for (int i = 0; i < 4; ++i) {
    int t1 = t1b + ty + 8 * i;
    int t2 = t2b + tx;
    if (t2 < N2F) tile[ty + 8 * i][tx] = htmp[t1 * N2F + t2];
  }
  __syncthreads();
  const float inv = fastrcp(__uint_as_float(*mx));
#pragma unroll
  for (int i = 0; i < 4; ++i) {
    int t2 = t2b + ty + 8 * i;
    int t1 = t1b + tx;
    if (t2 < N2F) h[t2 * 1024 + t1] = tile[tx][ty + 8 * i] * inv;
  }
}

extern "C" void kernel_launch(void* const* d_in, const int* in_sizes, int n_in,
                              void* d_out, int out_size, void* d_ws, size_t ws_size,
                              hipStream_t stream) {
  (void)in_sizes; (void)n_in; (void)ws_size;
  const float* Bv = (const float*)d_in[2];
  const float* Cv = (const float*)d_in[3];
  const float* X  = (const float*)d_in[4];
  float* out = (float*)d_out;
  char* ws = (char*)d_ws;
  float2* buf0 = (float2*)(ws);             // G, then AT
  float2* buf1 = (float2*)(ws + 3072000);   // GT, then Bb
  float*  htmp = (float*)(ws + 6144000);    // 384000 floats = 1,536,000 B
  unsigned* mx = (unsigned*)(ws + 7680000); // zeroed by expm_kernel
  float*  AGw  = (float*)(ws + 7680064);

  float* htail = out + (out_size - NFFTN);

  expm_kernel<<<1, 256, 0, stream>>>(X, AGw, mx);
  if (out_size >= 2 * FF * NN + NFFTN) {
    solve_kernel<true><<<(FF + 63) / 64, 256, 0, stream>>>(Bv, Cv, AGw, out, buf0);
  } else {
    solve_kernel<false><<<(FF + 63) / 64, 256, 0, stream>>>(Bv, Cv, AGw, out, buf0);
  }
  t1_kernel<<<dim3(32, 12), 256, 0, stream>>>(buf0, buf1);
  fftA_kernel<<<N2F, 256, 0, stream>>>(buf1, buf0);
  t2_kernel<<<dim3(32, 12), 256, 0, stream>>>(buf0, buf1);
  fftB_kernel<<<N1F, 384, 0, stream>>>(buf1, htmp, mx);
  t3_kernel<<<dim3(32, 12), 256, 0, stream>>>(htmp, mx, htail);
}